// Round 7
// baseline (155.474 us; speedup 1.0000x reference)
//
#include <hip/hip_runtime.h>
#include <math.h>

#define Vv 256
#define Ee 64
#define Hh 128
#define Nn 16384
#define Ll 24
#define G4 512      // 4*H
#define WB 16       // words per task (halved: fewer regs, 2 blocks/CU target)
#define NTHR 512    // 8 waves
#define NGRP (Nn / WB)      // 1024 groups
#define NTASK (NGRP * 2)    // 2048 tasks (group x dir) = grid

typedef _Float16 half8 __attribute__((ext_vector_type(8)));
typedef float f32x4 __attribute__((ext_vector_type(4)));

// ---- fused prep + sort (blocks 0..1023: prep; block 1024: counting sort in LDS)
// XGq[d][c][u][bank] (f32): (emb[c]@Wih_d[j] + bih[j]+bhh[j]) * scale(bank), j=bank*128+u.
//   scale = 0.5 for i,f,o banks (sigmoid(y)=0.5+0.5*tanh(y/2) -> Pade arg y/2); g raw.
// BP[d][kt][bank][g2][u][e] (f16): Whh_d[j][k]*scale(bank), k=kt*32+g2*8+e (B-frag order).
__global__ void prep_sort_kernel(const float* __restrict__ emb,
                                 const float* __restrict__ Wih_f, const float* __restrict__ Whh_f,
                                 const float* __restrict__ bih_f, const float* __restrict__ bhh_f,
                                 const float* __restrict__ Wih_b, const float* __restrict__ Whh_b,
                                 const float* __restrict__ bih_b, const float* __restrict__ bhh_b,
                                 const int* __restrict__ lens,
                                 _Float16* __restrict__ BP, float* __restrict__ XGq,
                                 int* __restrict__ order) {
  const int tid = threadIdx.x;
  if (blockIdx.x == 1024) {  // ---- sort block: hist + prefix + scatter, all in LDS
    __shared__ int hcnt[32];
    __shared__ int hcur[32];
    if (tid < 32) hcnt[tid] = 0;
    __syncthreads();
    for (int i = tid; i < Nn; i += 256) atomicAdd(&hcnt[lens[i]], 1);
    __syncthreads();
    if (tid == 0) {
      int s = 0;
      for (int b = 0; b <= Ll; b++) { hcur[b] = s; s += hcnt[b]; }
    }
    __syncthreads();
    for (int i = tid; i < Nn; i += 256) {
      int p = atomicAdd(&hcur[lens[i]], 1);
      order[p] = i;
    }
    return;
  }
  int i = blockIdx.x * 256 + tid;
  if (i < 2 * Vv * G4) {  // 262144
    int bank = i & 3, u = (i >> 2) & 127, c = (i >> 9) & 255, d = i >> 17;
    int j = bank * 128 + u;
    const float* Wih = d ? Wih_b : Wih_f;
    const float* bih = d ? bih_b : bih_f;
    const float* bhh = d ? bhh_b : bhh_f;
    float acc = bih[j] + bhh[j];
    const float4* e4 = (const float4*)(emb + c * Ee);
    const float4* w4 = (const float4*)(Wih + j * Ee);
#pragma unroll 4
    for (int k = 0; k < Ee / 4; k++) {
      float4 a = e4[k], b = w4[k];
      acc = fmaf(a.x, b.x, acc); acc = fmaf(a.y, b.y, acc);
      acc = fmaf(a.z, b.z, acc); acc = fmaf(a.w, b.w, acc);
    }
    XGq[i] = (bank == 2) ? acc : acc * 0.5f;
  }
  if (i < 2 * 4 * 4 * 4 * 128 * 8) {  // 131072
    int e = i & 7, u = (i >> 3) & 127, g2 = (i >> 10) & 3,
        bank = (i >> 12) & 3, kt = (i >> 14) & 3, d = (i >> 16) & 1;
    int j = bank * 128 + u;
    int k = kt * 32 + g2 * 8 + e;
    const float* Whh = d ? Whh_b : Whh_f;
    float w = Whh[j * Hh + k];
    BP[i] = (_Float16)((bank == 2) ? w : w * 0.5f);
  }
}

// Pade(5,4) tanh: tanh x ~= x(x^4+105x^2+945)/(15x^4+420x^2+945), num clamped to +-den
// (exact saturation beyond |x|~3.98). Err <= 4e-4 for |x|<=3, <=3e-5 for |x|<=1.5.
#define PADE_TANH(X, NUM, DEN)                                                \
    float X##_2 = (X) * (X);                                                  \
    float NUM = (X) * fmaf(X##_2, fmaf(X##_2, 1.0f, 105.0f), 945.0f);         \
    float DEN = fmaf(X##_2, fmaf(X##_2, 15.0f, 420.0f), 945.0f);              \
    NUM = fminf(fmaxf(NUM, -DEN), DEN);

// All-rational gates: sigmoid(y)=0.5+0.5*tanh(y/2), tanh via Pade; 2 rcp, 0 exp2 per set.
// i=0.5*Pi/di, f=0.5*Pf/df, o=0.5*Po/od, g=ng/dg; M=di*dg:
//   cn = f*c + i*g = (c*Pf*M + Pi*ng*df) * rcp(2*df*M)
//   hn = o*tanh(cn) = (Po*nc) * rcp(2*od*dc)
#define GATES(ACC, CS, HR, WLEN)                                              \
  _Pragma("unroll") for (int r = 0; r < 4; r++) {                             \
    float xi = ACC[0][r];                                                     \
    float xf = ACC[1][r];                                                     \
    float yg = ACC[2][r];                                                     \
    float xo = ACC[3][r];                                                     \
    PADE_TANH(xi, ni, di)                                                     \
    PADE_TANH(xf, nf, df)                                                     \
    PADE_TANH(yg, ng, dg)                                                     \
    PADE_TANH(xo, no, od)                                                     \
    float Pi = di + ni, Pf = df + nf, Po = od + no;                           \
    float M = di * dg;                                                        \
    float R1 = __builtin_amdgcn_rcpf((df + df) * M);                          \
    float cn = fmaf((CS[r] * Pf), M, (Pi * ng) * df) * R1;                    \
    PADE_TANH(cn, nc, dc)                                                     \
    float R2 = __builtin_amdgcn_rcpf((od + od) * dc);                         \
    float hn = (Po * nc) * R2;                                                \
    if (t < WLEN[r]) {                                                        \
      CS[r] = cn; HR[r] = hn;                                                 \
      hw[qg * 4 + r][u] = (_Float16)hn;                                       \
    }                                                                         \
  }

#define LOADX(XV, TT)                                                         \
  _Pragma("unroll") for (int r = 0; r < 4; r++) {                             \
    int pos = p0a[r] + sgn * (TT);                                            \
    pos = pos < 0 ? 0 : pos;                                                  \
    int c = idx_s[qg * 4 + r][pos];                                           \
    XV[r] = xq[(c << 7) + u];                                                 \
  }

// ---- main: 2048 tasks (16 sorted words x dir), one 8-wave block each, longest first.
// All 8 waves share the single 16-word M-tile; wave wv owns units [16wv,16wv+16).
// Whh in VGPRs (Bf, 64). Per step: prefetched XGq gather -> acc; ds_read h A-frags
// (double-buffered LDS, ONE barrier/step); 16 MFMA; all-rational gates; f16 h writeback.
__global__ __launch_bounds__(NTHR, 4) void bilstm_main(
    const int* __restrict__ cidx, const int* __restrict__ lens,
    const _Float16* __restrict__ BP, const float* __restrict__ XGq,
    const int* __restrict__ order, float* __restrict__ out) {
  __shared__ __align__(16) _Float16 hs[2][WB][136];  // dbuf; pad 136 -> 2-way bank (free)
  __shared__ int idx_s[WB][Ll];
  __shared__ int wid_s[WB];
  __shared__ int len_s[WB];

  const int tid = threadIdx.x;
  const int lane = tid & 63;
  const int wv = tid >> 6;        // wave 0..7
  const int qg = lane >> 4;       // quarter-group 0..3
  const int li = lane & 15;       // col within tile
  const int u = (wv << 4) + li;   // this lane's unit 0..127

  const int task = NTASK - 1 - (int)blockIdx.x;  // longest first
  const int g = task >> 1;
  const int d = task & 1;
  const int sgn = d ? -1 : 1;

  if (tid < WB) { int w = order[g * WB + tid]; wid_s[tid] = w; len_s[tid] = lens[w]; }
  __syncthreads();
  for (int i = tid; i < WB * Ll; i += NTHR) {
    int w = i / Ll, p = i - w * Ll;
    idx_s[w][p] = cidx[(size_t)wid_s[w] * Ll + p];
  }
  for (int i = tid; i < 2 * WB * 136; i += NTHR) ((_Float16*)hs)[i] = (_Float16)0.0f;
  __syncthreads();

  const int maxlen = len_s[WB - 1];  // ascending sort -> group max

  // Whh fragments -> registers (pre-scaled), once per task.
  half8 Bf[4][4];
  {
    const _Float16* BPd = BP + (size_t)d * 65536;
#pragma unroll
    for (int kt = 0; kt < 4; kt++)
#pragma unroll
      for (int bank = 0; bank < 4; bank++)
        Bf[kt][bank] = *(const half8*)(BPd + (size_t)((((kt * 4 + bank) * 4 + qg) * 128 + u) << 3));
  }

  const f32x4* xq = (const f32x4*)(XGq + (size_t)d * (Vv * G4));

  int wlen0[4], p0a[4];
#pragma unroll
  for (int r = 0; r < 4; r++) {
    wlen0[r] = len_s[qg * 4 + r];        // C/D row = (lane>>4)*4 + reg
    p0a[r] = d ? (wlen0[r] - 1) : 0;
  }
  float cst0[4], hreg0[4];
#pragma unroll
  for (int r = 0; r < 4; r++) { cst0[r] = 0.0f; hreg0[r] = 0.0f; }

  f32x4 x4a[4];
  if (maxlen > 0) { LOADX(x4a, 0); }

  for (int t = 0; t < maxlen; t++) {
    _Float16 (*hw)[136] = hs[t & 1];                 // write buffer
    const _Float16 (*hr)[136] = hs[(t ^ 1) & 1];     // read buffer = (t-1)&1

    // acc init from prefetched gather (loads issued last iteration)
    f32x4 acc0[4];
#pragma unroll
    for (int bank = 0; bank < 4; bank++)
#pragma unroll
      for (int r = 0; r < 4; r++) acc0[bank][r] = x4a[r][bank];

    if (t > 0) {  // h==0 at t=0: matmul contributes nothing
      half8 a0[4];
#pragma unroll
      for (int kt = 0; kt < 4; kt++)
        a0[kt] = *(const half8*)&hr[li][kt * 32 + qg * 8];
#pragma unroll
      for (int bank = 0; bank < 4; bank++) {
        f32x4 v0 = acc0[bank];
#pragma unroll
        for (int kt = 0; kt < 4; kt++)
          v0 = __builtin_amdgcn_mfma_f32_16x16x32_f16(a0[kt], Bf[kt][bank], v0, 0, 0, 0);
        acc0[bank] = v0;
      }
    }

    // prefetch next step's gather; L2 latency hides under the gates.
    if (t + 1 < maxlen) { LOADX(x4a, t + 1); }

    GATES(acc0, cst0, hreg0, wlen0);

    __syncthreads();  // writes to hs[t&1] visible before next step reads it
  }

  // output from fp32 regs
#pragma unroll
  for (int r = 0; r < 4; r++)
    out[(size_t)wid_s[qg * 4 + r] * (2 * Hh) + d * Hh + u] = hreg0[r];
}

extern "C" void kernel_launch(void* const* d_in, const int* in_sizes, int n_in,
                              void* d_out, int out_size, void* d_ws, size_t ws_size,
                              hipStream_t stream) {
  const int* cidx = (const int*)d_in[0];
  const int* lens = (const int*)d_in[1];
  const float* emb = (const float*)d_in[2];
  const float* Wih_f = (const float*)d_in[3];
  const float* Whh_f = (const float*)d_in[4];
  const float* bih_f = (const float*)d_in[5];
  const float* bhh_f = (const float*)d_in[6];
  const float* Wih_b = (const float*)d_in[7];
  const float* Whh_b = (const float*)d_in[8];
  const float* bih_b = (const float*)d_in[9];
  const float* bhh_b = (const float*)d_in[10];
  float* out = (float*)d_out;

  // ws: BP f16 [131072] = 256KB | XGq f32 [2*256*512] = 1MB | order[N]
  char* base = (char*)d_ws;
  _Float16* BP = (_Float16*)base;
  float* XGq = (float*)(base + 262144);
  int* order = (int*)(base + 262144 + 1048576);

  prep_sort_kernel<<<1025, 256, 0, stream>>>(
      emb, Wih_f, Whh_f, bih_f, bhh_f, Wih_b, Whh_b, bih_b, bhh_b, lens, BP, XGq, order);
  bilstm_main<<<NTASK, NTHR, 0, stream>>>(cidx, lens, BP, XGq, order, out);
}